// Round 13
// baseline (97.372 us; speedup 1.0000x reference)
//
#include <hip/hip_runtime.h>
#include <hip/hip_bf16.h>
#include <stdint.h>

// ---------------- helpers ----------------
__device__ __forceinline__ float bf2f(unsigned short u) {
    unsigned int x = ((unsigned int)u) << 16;
    return __uint_as_float(x);
}
__device__ __forceinline__ unsigned short f2bf(float f) {
    unsigned int x = __float_as_uint(f);
    unsigned int lsb = (x >> 16) & 1u;
    x += 0x7fffu + lsb;           // round-to-nearest-even
    return (unsigned short)(x >> 16);
}
__device__ __forceinline__ unsigned int pack2bf(float lo, float hi) {
    return (unsigned int)f2bf(lo) | ((unsigned int)f2bf(hi) << 16);
}
__device__ __forceinline__ float loadF(const void* p, int i, int isbf) {
    return isbf ? bf2f(((const unsigned short*)p)[i]) : ((const float*)p)[i];
}

#define TS 68
#define CHMAX 4224        // LDS edge-chunk capacity per binning block

// ---------------- init: zero bcnt + dtype flags ----------------
// flags[0] = floats bf16(1)/f32(0); flags[1] = edge_index int64(1)/int32(0)
__global__ void k_init(const void* x, const void* eidx, int* flags, int* bcnt, int B) {
    int t = threadIdx.x;   // 1024
    for (int b = t; b < B; b += blockDim.x) bcnt[b] = 0;
    if (t < 64) {
        const unsigned short* u = (const unsigned short*)x;
        float a = fabsf(bf2f(u[2 * t]));
        bool ok = (a == 0.0f) || (a > 1e-30f && a < 1e4f);
        unsigned long long mbf = __ballot(ok);
        if (t == 0) flags[0] = (mbf == ~0ULL) ? 1 : 0;
    } else if (t < 128) {
        int l = t - 64;
        const int* ip = (const int*)eidx;
        unsigned long long mi64 = __ballot(ip[2 * l + 1] == 0);
        if (l == 0) flags[1] = (mi64 == ~0ULL) ? 1 : 0;
    }
}

// ---------------- fused: edge binning (blocks 0..G-1) + consts (block G) -------
// Binning: single global pass; per-block edge chunk staged in LDS, then
// histogram -> segment reserve -> scatter from LDS.
// Consts (block G): M = W1^3 W2 ; cvecs = {g3,g2,g1,b2}
// Shared dynamic LDS region: max(consts 56064 B, bin (2*CHMAX+3*B)*4 B)
__global__ void k_bin(const void* eidx, int E, int rsh, int B, int cap,
                      unsigned int* bins, int* bcnt, const int* flags,
                      const void* W1, const void* b1, const void* W2, const void* b2,
                      float* M, float* cvecs, int nbin) {
    extern __shared__ char smem[];
    if ((int)blockIdx.x == nbin) {   // ---- consts block ----
        float* A   = (float*)smem;                 // 64*64
        float* T1  = A + 4096;                     // 64*TS
        float* T2  = T1 + 64 * TS;                 // 64*TS
        float* B2s = T2 + 64 * TS;                 // 64*16
        float* bv  = B2s + 1024;                   // 64
        float* bw1 = bv + 64;                      // 64
        float* bw2 = bw1 + 64;                     // 64
        int bf = flags[0];
        int t = threadIdx.x;   // 512 threads; use 256
        if (t < 256) {
            for (int i = t; i < 4096; i += 256) A[i] = loadF(W1, i, bf);
            for (int i = t; i < 1024; i += 256) B2s[i] = loadF(W2, i, bf);
            if (t < 64) bv[t] = loadF(b1, t, bf);
        }
        __syncthreads();
        if (t < 256) {
            const int i0 = (t >> 4) * 4;
            const int j0 = (t & 15) * 4;
            {   // T1 = A @ A
                float acc[4][4] = {};
#pragma unroll 8
                for (int k = 0; k < 64; ++k) {
                    float a0 = A[(i0 + 0) * 64 + k];
                    float a1 = A[(i0 + 1) * 64 + k];
                    float a2 = A[(i0 + 2) * 64 + k];
                    float a3 = A[(i0 + 3) * 64 + k];
                    float4 bq = *(const float4*)&A[k * 64 + j0];
                    acc[0][0] += a0 * bq.x; acc[0][1] += a0 * bq.y; acc[0][2] += a0 * bq.z; acc[0][3] += a0 * bq.w;
                    acc[1][0] += a1 * bq.x; acc[1][1] += a1 * bq.y; acc[1][2] += a1 * bq.z; acc[1][3] += a1 * bq.w;
                    acc[2][0] += a2 * bq.x; acc[2][1] += a2 * bq.y; acc[2][2] += a2 * bq.z; acc[2][3] += a2 * bq.w;
                    acc[3][0] += a3 * bq.x; acc[3][1] += a3 * bq.y; acc[3][2] += a3 * bq.z; acc[3][3] += a3 * bq.w;
                }
#pragma unroll
                for (int ii = 0; ii < 4; ++ii)
                    *(float4*)&T1[(i0 + ii) * TS + j0] = make_float4(acc[ii][0], acc[ii][1], acc[ii][2], acc[ii][3]);
            }
            if (t < 64) {
                float acc = 0.f;
#pragma unroll 8
                for (int i = 0; i < 64; ++i) acc += bv[i] * A[i * 64 + t];
                bw1[t] = acc;
            }
        }
        __syncthreads();
        if (t < 256) {
            const int i0 = (t >> 4) * 4;
            const int j0 = (t & 15) * 4;
            {   // T2 = T1 @ A
                float acc[4][4] = {};
#pragma unroll 8
                for (int k = 0; k < 64; ++k) {
                    float a0 = T1[(i0 + 0) * TS + k];
                    float a1 = T1[(i0 + 1) * TS + k];
                    float a2 = T1[(i0 + 2) * TS + k];
                    float a3 = T1[(i0 + 3) * TS + k];
                    float4 bq = *(const float4*)&A[k * 64 + j0];
                    acc[0][0] += a0 * bq.x; acc[0][1] += a0 * bq.y; acc[0][2] += a0 * bq.z; acc[0][3] += a0 * bq.w;
                    acc[1][0] += a1 * bq.x; acc[1][1] += a1 * bq.y; acc[1][2] += a1 * bq.z; acc[1][3] += a1 * bq.w;
                    acc[2][0] += a2 * bq.x; acc[2][1] += a2 * bq.y; acc[2][2] += a2 * bq.z; acc[2][3] += a2 * bq.w;
                    acc[3][0] += a3 * bq.x; acc[3][1] += a3 * bq.y; acc[3][2] += a3 * bq.z; acc[3][3] += a3 * bq.w;
                }
#pragma unroll
                for (int ii = 0; ii < 4; ++ii)
                    *(float4*)&T2[(i0 + ii) * TS + j0] = make_float4(acc[ii][0], acc[ii][1], acc[ii][2], acc[ii][3]);
            }
            if (t < 64) {
                float acc = 0.f;
#pragma unroll 8
                for (int i = 0; i < 64; ++i) acc += bw1[i] * A[i * 64 + t];
                bw2[t] = acc;
            }
        }
        __syncthreads();
        if (t < 256) {
            {   // M = T2 @ B2 (64x16)
                int i = t >> 2, j0m = (t & 3) * 4;
                float4 acc = {0.f, 0.f, 0.f, 0.f};
#pragma unroll 8
                for (int k = 0; k < 64; ++k) {
                    float a = T2[i * TS + k];
                    float4 bq = *(const float4*)&B2s[k * 16 + j0m];
                    acc.x += a * bq.x; acc.y += a * bq.y; acc.z += a * bq.z; acc.w += a * bq.w;
                }
                *(float4*)&M[i * 16 + j0m] = acc;
            }
            if (t < 16) {
                float a3 = 0.f, a2 = 0.f, a1 = 0.f;
#pragma unroll 8
                for (int i = 0; i < 64; ++i) {
                    float w = B2s[i * 16 + t];
                    a3 += bw2[i] * w;
                    a2 += bw1[i] * w;
                    a1 += bv[i] * w;
                }
                cvecs[t] = a3;
                cvecs[16 + t] = a2;
                cvecs[32 + t] = a1;
                cvecs[48 + t] = loadF(b2, t, flags[0]);
            }
        }
        return;
    }
    // ---- binning blocks: single global pass, LDS-staged chunk ----
    int* chunk_s = (int*)smem;             // CHMAX
    int* chunk_d = chunk_s + CHMAX;        // CHMAX
    int* hist    = chunk_d + CHMAX;        // B
    int* base_s  = hist + B;               // B
    int* cur     = base_s + B;             // B
    const int i64 = flags[1];
    const int t = threadIdx.x, nt = blockDim.x;
    const long long i0 = (long long)blockIdx.x * E / nbin;
    const long long i1 = (long long)(blockIdx.x + 1) * E / nbin;
    const long long* e64 = (const long long*)eidx;
    const int* e32 = (const int*)eidx;
    const int mask = (1 << rsh) - 1;

    for (long long c0 = i0; c0 < i1; c0 += CHMAX) {
        int m = (int)((i1 - c0) < CHMAX ? (i1 - c0) : CHMAX);
        for (int b = t; b < B; b += nt) { hist[b] = 0; cur[b] = 0; }
        __syncthreads();
        // load chunk once + histogram
        for (int k = t; k < m; k += nt) {
            long long i = c0 + k;
            int d, s;
            if (i64) { d = (int)e64[E + i]; s = (int)e64[i]; }
            else     { d = e32[E + i];     s = e32[i]; }
            chunk_s[k] = s;
            chunk_d[k] = d;
            atomicAdd(&hist[d >> rsh], 1);
        }
        __syncthreads();
        // reserve contiguous segments
        for (int b = t; b < B; b += nt) {
            int c = hist[b];
            base_s[b] = c ? atomicAdd(&bcnt[b], c) : 0;
        }
        __syncthreads();
        // scatter from LDS
        for (int k = t; k < m; k += nt) {
            int d = chunk_d[k], s = chunk_s[k];
            int b = d >> rsh;
            int pos = base_s[b] + atomicAdd(&cur[b], 1);
            if (pos >= cap) pos = cap - 1;     // paranoia guard
            bins[(size_t)b * cap + pos] = ((unsigned int)s << rsh) | (unsigned int)(d & mask);
        }
        __syncthreads();
    }
}

// ---------------- per-bucket CSR build + fused z0 = bf16(dinv * x@M) ----------
// meta[v] = { rstart, len, dinv_bits, 0 }
__global__ void k_csr(const unsigned int* bins, const int* bcnt, int cap, int rsh,
                      int n, int* colb, int4* meta,
                      const void* x, const float* M, unsigned short* z0,
                      const int* flags) {
    __shared__ int dh[128], db[128], ch[128];
    __shared__ float Ms[1024];
    __shared__ float xs[128 * 65];
    const int R = 1 << rsh;                // 128
    const int b = blockIdx.x, t = threadIdx.x, nt = blockDim.x;   // 256
    const int mask = R - 1;
    for (int r = t; r < R; r += nt) { dh[r] = 0; ch[r] = 0; }
    __syncthreads();
    int cnt = bcnt[b]; if (cnt > cap) cnt = cap;
    const unsigned int* eb = bins + (size_t)b * cap;
    for (int e = t; e < cnt; e += nt)
        atomicAdd(&dh[eb[e] & mask], 1);
    __syncthreads();
    if (t < R) db[t] = dh[t];
    __syncthreads();
    for (int off = 1; off < R; off <<= 1) {
        int add = 0;
        if (t < R && t >= off) add = db[t - off];
        __syncthreads();
        if (t < R) db[t] += add;
        __syncthreads();
    }
    const int v0 = b << rsh;
    const int gbase = b * cap;
    if (t < R) {
        int v = v0 + t;
        if (v < n) {
            int len = dh[t];
            float dv = rsqrtf((float)(len + 1));
            meta[v] = make_int4(gbase + db[t] - len, len, __float_as_int(dv), 0);
        }
    }
    __syncthreads();
    for (int e = t; e < cnt; e += nt) {
        unsigned int w = eb[e];
        int r = w & mask;
        int pos = (db[r] - dh[r]) + atomicAdd(&ch[r], 1);
        colb[gbase + pos] = (int)(w >> rsh);
    }
    // ---- fused xm: z0[v] = bf16(dinv * (x[v] @ M)) for this bucket ----
    const int bf = flags[0];
    ((float4*)Ms)[t] = ((const float4*)M)[t];
    int nvalid = n - v0;
    if (nvalid > R) nvalid = R;
    if (nvalid > 0) {
        if (!bf) {
            const float* xf = (const float*)x + (size_t)v0 * 64;
            for (int i = t; i < nvalid * 16; i += nt) {
                int r = i >> 4, c4 = (i & 15) * 4;
                float4 v = *(const float4*)&xf[r * 64 + c4];
                float* xp = &xs[r * 65 + c4];
                xp[0] = v.x; xp[1] = v.y; xp[2] = v.z; xp[3] = v.w;
            }
        } else {
            const unsigned short* xu = (const unsigned short*)x + (size_t)v0 * 64;
            for (int i = t; i < nvalid * 16; i += nt) {
                int r = i >> 4, c4 = (i & 15) * 4;
                ushort4 v = *(const ushort4*)&xu[r * 64 + c4];
                float* xp = &xs[r * 65 + c4];
                xp[0] = bf2f(v.x); xp[1] = bf2f(v.y); xp[2] = bf2f(v.z); xp[3] = bf2f(v.w);
            }
        }
    }
    __syncthreads();
    {
        int r = t >> 1, h = t & 1;         // 2 threads per row, 8 channels each
        int v = v0 + r;
        if (v < n) {
            float a0 = 0.f, a1 = 0.f, a2 = 0.f, a3 = 0.f;
            float a4 = 0.f, a5 = 0.f, a6 = 0.f, a7 = 0.f;
#pragma unroll 8
            for (int k = 0; k < 64; ++k) {
                float xv = xs[r * 65 + k];
                const float* mp = &Ms[k * 16 + h * 8];
                a0 += xv * mp[0]; a1 += xv * mp[1]; a2 += xv * mp[2]; a3 += xv * mp[3];
                a4 += xv * mp[4]; a5 += xv * mp[5]; a6 += xv * mp[6]; a7 += xv * mp[7];
            }
            float dv = rsqrtf((float)(dh[r] + 1));
            int4 ov;
            ov.x = (int)pack2bf(dv * a0, dv * a1);
            ov.y = (int)pack2bf(dv * a2, dv * a3);
            ov.z = (int)pack2bf(dv * a4, dv * a5);
            ov.w = (int)pack2bf(dv * a6, dv * a7);
            *(int4*)&z0[(size_t)v * 16 + h * 8] = ov;
        }
    }
}

// ---------------- pull propagation: bf16 z, packed meta, 4 lanes/node ---------
// sum = z[v] + sum_{s in N(v)} z[s]
// non-final: zout = bf16(dinv^2*sum + dinv*cvec) ; final: yout = dinv*sum + cvec
__global__ void k_prop(const unsigned short* zin, void* yout, const int4* meta,
                       const int* colb, const float* cvec,
                       int n, int is_final, const int* flags) {
    int tid = blockIdx.x * blockDim.x + threadIdx.x;
    int v = tid >> 2, q = tid & 3;
    if (v >= n) return;
    int4 m = meta[v];                      // {rstart, len, dinv_bits, 0}
    int beg = m.x, len = m.y;
    ushort4 sv = *(const ushort4*)&zin[(size_t)v * 16 + q * 4];   // self-loop
    float4 acc = make_float4(bf2f(sv.x), bf2f(sv.y), bf2f(sv.z), bf2f(sv.w));
    int j = beg, end = beg + len;
    for (; j + 4 <= end; j += 4) {         // 4 gathers in flight
        int c0 = colb[j], c1 = colb[j + 1], c2 = colb[j + 2], c3 = colb[j + 3];
        ushort4 za = *(const ushort4*)&zin[(size_t)c0 * 16 + q * 4];
        ushort4 zb = *(const ushort4*)&zin[(size_t)c1 * 16 + q * 4];
        ushort4 zc = *(const ushort4*)&zin[(size_t)c2 * 16 + q * 4];
        ushort4 zd = *(const ushort4*)&zin[(size_t)c3 * 16 + q * 4];
        acc.x += (bf2f(za.x) + bf2f(zb.x)) + (bf2f(zc.x) + bf2f(zd.x));
        acc.y += (bf2f(za.y) + bf2f(zb.y)) + (bf2f(zc.y) + bf2f(zd.y));
        acc.z += (bf2f(za.z) + bf2f(zb.z)) + (bf2f(zc.z) + bf2f(zd.z));
        acc.w += (bf2f(za.w) + bf2f(zb.w)) + (bf2f(zc.w) + bf2f(zd.w));
    }
    for (; j < end; ++j) {
        int c0 = colb[j];
        ushort4 za = *(const ushort4*)&zin[(size_t)c0 * 16 + q * 4];
        acc.x += bf2f(za.x); acc.y += bf2f(za.y); acc.z += bf2f(za.z); acc.w += bf2f(za.w);
    }
    float dv = __int_as_float(m.z);
    float a = is_final ? dv : dv * dv;
    float b = is_final ? 1.0f : dv;
    float4 cv = *(const float4*)&cvec[q * 4];
    float4 val;
    val.x = a * acc.x + b * cv.x;
    val.y = a * acc.y + b * cv.y;
    val.z = a * acc.z + b * cv.z;
    val.w = a * acc.w + b * cv.w;
    int o = v * 16 + q * 4;
    if (is_final && !flags[0]) {
        *(float4*)&((float*)yout)[o] = val;
    } else {
        ushort4 ov;
        ov.x = f2bf(val.x); ov.y = f2bf(val.y); ov.z = f2bf(val.z); ov.w = f2bf(val.w);
        *(ushort4*)&((unsigned short*)yout)[o] = ov;
    }
}

// ---------------- launch ----------------
extern "C" void kernel_launch(void* const* d_in, const int* in_sizes, int n_in,
                              void* d_out, int out_size, void* d_ws, size_t ws_size,
                              hipStream_t stream) {
    const void* x  = d_in[0];
    const void* W1 = d_in[1];
    const void* b1 = d_in[2];
    const void* W2 = d_in[3];
    const void* b2 = d_in[4];
    const void* ei = d_in[5];

    const int n = in_sizes[0] / 64;       // 100000
    const int E = in_sizes[5] / 2;        // 1000000

    const int rsh = 7;
    const int B = (n + (1 << rsh) - 1) >> rsh;       // 782
    const int avg = E / B;
    int cap = avg + avg / 4 + 128;                    // mean + ~12 sigma slack
    cap = (cap + 31) & ~31;

    char* base = (char*)d_ws;
    size_t off = 0;
    auto carve = [&](size_t bytes) -> void* {
        void* r = base + off;
        off = (off + bytes + 255) & ~(size_t)255;
        return r;
    };
    int*            flags  = (int*)carve(8);
    int*            bcnt   = (int*)carve((size_t)B * 4);
    unsigned int*   bins   = (unsigned int*)carve((size_t)B * cap * 4);
    int*            colb   = (int*)carve((size_t)B * cap * 4);
    int4*           meta   = (int4*)carve((size_t)n * 16);
    float*          Mm     = (float*)carve(1024 * 4);
    float*          cvecs  = (float*)carve(64 * 4);
    unsigned short* z0     = (unsigned short*)carve((size_t)n * 16 * 2);
    unsigned short* z1     = (unsigned short*)carve((size_t)n * 16 * 2);
    (void)ws_size; (void)n_in; (void)out_size;

    const int nbin = 240;
    // dynamic LDS: max(consts 14016 floats, bin 2*CHMAX+3*B ints)
    size_t sh_consts = (size_t)(4096 + 64 * TS + 64 * TS + 1024 + 192) * 4;
    size_t sh_bin    = (size_t)(2 * CHMAX + 3 * B) * 4;
    size_t shmem = sh_consts > sh_bin ? sh_consts : sh_bin;

    k_init<<<1, 1024, 0, stream>>>(x, ei, flags, bcnt, B);
    k_bin<<<nbin + 1, 512, shmem, stream>>>(ei, E, rsh, B, cap, bins, bcnt,
                                            flags, W1, b1, W2, b2, Mm, cvecs, nbin);
    k_csr<<<B, 256, 0, stream>>>(bins, bcnt, cap, rsh, n, colb, meta, x, Mm, z0, flags);

    const int pgrid = (n * 4 + 255) / 256;
    k_prop<<<pgrid, 256, 0, stream>>>(z0, z1, meta, colb, cvecs + 0,  n, 0, flags);
    k_prop<<<pgrid, 256, 0, stream>>>(z1, z0, meta, colb, cvecs + 16, n, 0, flags);
    k_prop<<<pgrid, 256, 0, stream>>>(z0, z1, meta, colb, cvecs + 32, n, 0, flags);
    k_prop<<<pgrid, 256, 0, stream>>>(z1, d_out, meta, colb, cvecs + 48, n, 1, flags);
}

// Round 14
// 97.103 us; speedup vs baseline: 1.0028x; 1.0028x over previous
//
#include <hip/hip_runtime.h>
#include <hip/hip_bf16.h>
#include <stdint.h>

// ---------------- helpers ----------------
__device__ __forceinline__ float bf2f(unsigned short u) {
    unsigned int x = ((unsigned int)u) << 16;
    return __uint_as_float(x);
}
__device__ __forceinline__ unsigned short f2bf(float f) {
    unsigned int x = __float_as_uint(f);
    unsigned int lsb = (x >> 16) & 1u;
    x += 0x7fffu + lsb;           // round-to-nearest-even
    return (unsigned short)(x >> 16);
}
__device__ __forceinline__ unsigned int pack2bf(float lo, float hi) {
    return (unsigned int)f2bf(lo) | ((unsigned int)f2bf(hi) << 16);
}
__device__ __forceinline__ float loadF(const void* p, int i, int isbf) {
    return isbf ? bf2f(((const unsigned short*)p)[i]) : ((const float*)p)[i];
}

// ---------------- init: zero bcnt + dtype flags ----------------
// flags[0] = floats bf16(1)/f32(0); flags[1] = edge_index int64(1)/int32(0)
__global__ void k_init(const void* x, const void* eidx, int* flags, int* bcnt, int B) {
    int t = threadIdx.x;   // 1024
    for (int b = t; b < B; b += blockDim.x) bcnt[b] = 0;
    if (t < 64) {
        const unsigned short* u = (const unsigned short*)x;
        float a = fabsf(bf2f(u[2 * t]));
        bool ok = (a == 0.0f) || (a > 1e-30f && a < 1e4f);
        unsigned long long mbf = __ballot(ok);
        if (t == 0) flags[0] = (mbf == ~0ULL) ? 1 : 0;
    } else if (t < 128) {
        int l = t - 64;
        const int* ip = (const int*)eidx;
        unsigned long long mi64 = __ballot(ip[2 * l + 1] == 0);
        if (l == 0) flags[1] = (mi64 == ~0ULL) ? 1 : 0;
    }
}

// ---------------- fused: edge binning (blocks 0..G-1) + consts (block G) -------
// Binning: bucket = dst >> rsh (R=128). Packed word = (src << rsh) | (dst & R-1).
// Consts: M = W1^3 W2 ; cvecs = {g3=b1W1^2W2, g2=b1W1W2, g1=b1W2, b2}
#define TS 68
__global__ void k_bin(const void* eidx, int E, int rsh, int B, int cap,
                      unsigned int* bins, int* bcnt, const int* flags,
                      const void* W1, const void* b1, const void* W2, const void* b2,
                      float* M, float* cvecs, int nbin) {
    if ((int)blockIdx.x == nbin) {   // ---- consts block ----
        __shared__ float A[64 * 64];
        __shared__ float T1[64 * TS];
        __shared__ float T2[64 * TS];
        __shared__ float B2s[64 * 16];
        __shared__ float bv[64], bw1[64], bw2[64];
        int bf = flags[0];
        int t = threadIdx.x;   // 512 threads; use 256
        if (t < 256) {
            for (int i = t; i < 4096; i += 256) A[i] = loadF(W1, i, bf);
            for (int i = t; i < 1024; i += 256) B2s[i] = loadF(W2, i, bf);
            if (t < 64) bv[t] = loadF(b1, t, bf);
        }
        __syncthreads();
        if (t < 256) {
            const int i0 = (t >> 4) * 4;
            const int j0 = (t & 15) * 4;
            {   // T1 = A @ A
                float acc[4][4] = {};
#pragma unroll 8
                for (int k = 0; k < 64; ++k) {
                    float a0 = A[(i0 + 0) * 64 + k];
                    float a1 = A[(i0 + 1) * 64 + k];
                    float a2 = A[(i0 + 2) * 64 + k];
                    float a3 = A[(i0 + 3) * 64 + k];
                    float4 bq = *(const float4*)&A[k * 64 + j0];
                    acc[0][0] += a0 * bq.x; acc[0][1] += a0 * bq.y; acc[0][2] += a0 * bq.z; acc[0][3] += a0 * bq.w;
                    acc[1][0] += a1 * bq.x; acc[1][1] += a1 * bq.y; acc[1][2] += a1 * bq.z; acc[1][3] += a1 * bq.w;
                    acc[2][0] += a2 * bq.x; acc[2][1] += a2 * bq.y; acc[2][2] += a2 * bq.z; acc[2][3] += a2 * bq.w;
                    acc[3][0] += a3 * bq.x; acc[3][1] += a3 * bq.y; acc[3][2] += a3 * bq.z; acc[3][3] += a3 * bq.w;
                }
#pragma unroll
                for (int ii = 0; ii < 4; ++ii)
                    *(float4*)&T1[(i0 + ii) * TS + j0] = make_float4(acc[ii][0], acc[ii][1], acc[ii][2], acc[ii][3]);
            }
            if (t < 64) {
                float acc = 0.f;
#pragma unroll 8
                for (int i = 0; i < 64; ++i) acc += bv[i] * A[i * 64 + t];
                bw1[t] = acc;
            }
        }
        __syncthreads();
        if (t < 256) {
            const int i0 = (t >> 4) * 4;
            const int j0 = (t & 15) * 4;
            {   // T2 = T1 @ A
                float acc[4][4] = {};
#pragma unroll 8
                for (int k = 0; k < 64; ++k) {
                    float a0 = T1[(i0 + 0) * TS + k];
                    float a1 = T1[(i0 + 1) * TS + k];
                    float a2 = T1[(i0 + 2) * TS + k];
                    float a3 = T1[(i0 + 3) * TS + k];
                    float4 bq = *(const float4*)&A[k * 64 + j0];
                    acc[0][0] += a0 * bq.x; acc[0][1] += a0 * bq.y; acc[0][2] += a0 * bq.z; acc[0][3] += a0 * bq.w;
                    acc[1][0] += a1 * bq.x; acc[1][1] += a1 * bq.y; acc[1][2] += a1 * bq.z; acc[1][3] += a1 * bq.w;
                    acc[2][0] += a2 * bq.x; acc[2][1] += a2 * bq.y; acc[2][2] += a2 * bq.z; acc[2][3] += a2 * bq.w;
                    acc[3][0] += a3 * bq.x; acc[3][1] += a3 * bq.y; acc[3][2] += a3 * bq.z; acc[3][3] += a3 * bq.w;
                }
#pragma unroll
                for (int ii = 0; ii < 4; ++ii)
                    *(float4*)&T2[(i0 + ii) * TS + j0] = make_float4(acc[ii][0], acc[ii][1], acc[ii][2], acc[ii][3]);
            }
            if (t < 64) {
                float acc = 0.f;
#pragma unroll 8
                for (int i = 0; i < 64; ++i) acc += bw1[i] * A[i * 64 + t];
                bw2[t] = acc;
            }
        }
        __syncthreads();
        if (t < 256) {
            {   // M = T2 @ B2 (64x16)
                int i = t >> 2, j0m = (t & 3) * 4;
                float4 acc = {0.f, 0.f, 0.f, 0.f};
#pragma unroll 8
                for (int k = 0; k < 64; ++k) {
                    float a = T2[i * TS + k];
                    float4 bq = *(const float4*)&B2s[k * 16 + j0m];
                    acc.x += a * bq.x; acc.y += a * bq.y; acc.z += a * bq.z; acc.w += a * bq.w;
                }
                *(float4*)&M[i * 16 + j0m] = acc;
            }
            if (t < 16) {
                float a3 = 0.f, a2 = 0.f, a1 = 0.f;
#pragma unroll 8
                for (int i = 0; i < 64; ++i) {
                    float w = B2s[i * 16 + t];
                    a3 += bw2[i] * w;
                    a2 += bw1[i] * w;
                    a1 += bv[i] * w;
                }
                cvecs[t] = a3;
                cvecs[16 + t] = a2;
                cvecs[32 + t] = a1;
                cvecs[48 + t] = loadF(b2, t, flags[0]);
            }
        }
        return;
    }
    // ---- binning blocks ----
    extern __shared__ int sh[];            // 2*B ints
    int* hist   = sh;
    int* base_s = sh + B;
    const int i64 = flags[1];
    const int t = threadIdx.x, nt = blockDim.x;
    const long long i0 = (long long)blockIdx.x * E / nbin;
    const long long i1 = (long long)(blockIdx.x + 1) * E / nbin;
    const long long* e64 = (const long long*)eidx;
    const int* e32 = (const int*)eidx;
    const int mask = (1 << rsh) - 1;

    for (int b = t; b < B; b += nt) hist[b] = 0;
    __syncthreads();
    for (long long i = i0 + t; i < i1; i += nt) {
        int d = i64 ? (int)e64[E + i] : e32[E + i];
        atomicAdd(&hist[d >> rsh], 1);
    }
    __syncthreads();
    for (int b = t; b < B; b += nt) {
        int c = hist[b];
        base_s[b] = c ? atomicAdd(&bcnt[b], c) : 0;
        hist[b] = 0;
    }
    __syncthreads();
    for (long long i = i0 + t; i < i1; i += nt) {
        int d, s;
        if (i64) { d = (int)e64[E + i]; s = (int)e64[i]; }
        else     { d = e32[E + i];     s = e32[i]; }
        int b = d >> rsh;
        int pos = base_s[b] + atomicAdd(&hist[b], 1);
        if (pos >= cap) pos = cap - 1;     // paranoia guard
        bins[(size_t)b * cap + pos] = ((unsigned int)s << rsh) | (unsigned int)(d & mask);
    }
}

// ---------------- per-bucket CSR build + fused z0 = bf16(dinv * x@M) ----------
// meta[v] = { rstart, len, dinv_bits, 0 }
__global__ void k_csr(const unsigned int* bins, const int* bcnt, int cap, int rsh,
                      int n, int* colb, int4* meta,
                      const void* x, const float* M, unsigned short* z0,
                      const int* flags) {
    __shared__ int dh[128], db[128], ch[128];
    __shared__ float Ms[1024];
    __shared__ float xs[128 * 65];
    const int R = 1 << rsh;                // 128
    const int b = blockIdx.x, t = threadIdx.x, nt = blockDim.x;   // 256
    const int mask = R - 1;
    for (int r = t; r < R; r += nt) { dh[r] = 0; ch[r] = 0; }
    __syncthreads();
    int cnt = bcnt[b]; if (cnt > cap) cnt = cap;
    const unsigned int* eb = bins + (size_t)b * cap;
    for (int e = t; e < cnt; e += nt)
        atomicAdd(&dh[eb[e] & mask], 1);
    __syncthreads();
    if (t < R) db[t] = dh[t];
    __syncthreads();
    for (int off = 1; off < R; off <<= 1) {
        int add = 0;
        if (t < R && t >= off) add = db[t - off];
        __syncthreads();
        if (t < R) db[t] += add;
        __syncthreads();
    }
    const int v0 = b << rsh;
    const int gbase = b * cap;
    if (t < R) {
        int v = v0 + t;
        if (v < n) {
            int len = dh[t];
            float dv = rsqrtf((float)(len + 1));
            meta[v] = make_int4(gbase + db[t] - len, len, __float_as_int(dv), 0);
        }
    }
    __syncthreads();
    for (int e = t; e < cnt; e += nt) {
        unsigned int w = eb[e];
        int r = w & mask;
        int pos = (db[r] - dh[r]) + atomicAdd(&ch[r], 1);
        colb[gbase + pos] = (int)(w >> rsh);
    }
    // ---- fused xm: z0[v] = bf16(dinv * (x[v] @ M)) for this bucket ----
    const int bf = flags[0];
    ((float4*)Ms)[t] = ((const float4*)M)[t];
    int nvalid = n - v0;
    if (nvalid > R) nvalid = R;
    if (nvalid > 0) {
        if (!bf) {
            const float* xf = (const float*)x + (size_t)v0 * 64;
            for (int i = t; i < nvalid * 16; i += nt) {
                int r = i >> 4, c4 = (i & 15) * 4;
                float4 v = *(const float4*)&xf[r * 64 + c4];
                float* xp = &xs[r * 65 + c4];
                xp[0] = v.x; xp[1] = v.y; xp[2] = v.z; xp[3] = v.w;
            }
        } else {
            const unsigned short* xu = (const unsigned short*)x + (size_t)v0 * 64;
            for (int i = t; i < nvalid * 16; i += nt) {
                int r = i >> 4, c4 = (i & 15) * 4;
                ushort4 v = *(const ushort4*)&xu[r * 64 + c4];
                float* xp = &xs[r * 65 + c4];
                xp[0] = bf2f(v.x); xp[1] = bf2f(v.y); xp[2] = bf2f(v.z); xp[3] = bf2f(v.w);
            }
        }
    }
    __syncthreads();
    {
        int r = t >> 1, h = t & 1;         // 2 threads per row, 8 channels each
        int v = v0 + r;
        if (v < n) {
            float a0 = 0.f, a1 = 0.f, a2 = 0.f, a3 = 0.f;
            float a4 = 0.f, a5 = 0.f, a6 = 0.f, a7 = 0.f;
#pragma unroll 8
            for (int k = 0; k < 64; ++k) {
                float xv = xs[r * 65 + k];
                const float* mp = &Ms[k * 16 + h * 8];
                a0 += xv * mp[0]; a1 += xv * mp[1]; a2 += xv * mp[2]; a3 += xv * mp[3];
                a4 += xv * mp[4]; a5 += xv * mp[5]; a6 += xv * mp[6]; a7 += xv * mp[7];
            }
            float dv = rsqrtf((float)(dh[r] + 1));
            int4 ov;
            ov.x = (int)pack2bf(dv * a0, dv * a1);
            ov.y = (int)pack2bf(dv * a2, dv * a3);
            ov.z = (int)pack2bf(dv * a4, dv * a5);
            ov.w = (int)pack2bf(dv * a6, dv * a7);
            *(int4*)&z0[(size_t)v * 16 + h * 8] = ov;
        }
    }
}

// ---------------- pull propagation: bf16 z, packed meta, 4 lanes/node ---------
// sum = z[v] + sum_{s in N(v)} z[s]
// non-final: zout = bf16(dinv^2*sum + dinv*cvec) ; final: yout = dinv*sum + cvec
__global__ void k_prop(const unsigned short* zin, void* yout, const int4* meta,
                       const int* colb, const float* cvec,
                       int n, int is_final, const int* flags) {
    int tid = blockIdx.x * blockDim.x + threadIdx.x;
    int v = tid >> 2, q = tid & 3;
    if (v >= n) return;
    int4 m = meta[v];                      // {rstart, len, dinv_bits, 0}
    int beg = m.x, len = m.y;
    ushort4 sv = *(const ushort4*)&zin[(size_t)v * 16 + q * 4];   // self-loop
    float4 acc = make_float4(bf2f(sv.x), bf2f(sv.y), bf2f(sv.z), bf2f(sv.w));
    int j = beg, end = beg + len;
    for (; j + 4 <= end; j += 4) {         // 4 gathers in flight
        int c0 = colb[j], c1 = colb[j + 1], c2 = colb[j + 2], c3 = colb[j + 3];
        ushort4 za = *(const ushort4*)&zin[(size_t)c0 * 16 + q * 4];
        ushort4 zb = *(const ushort4*)&zin[(size_t)c1 * 16 + q * 4];
        ushort4 zc = *(const ushort4*)&zin[(size_t)c2 * 16 + q * 4];
        ushort4 zd = *(const ushort4*)&zin[(size_t)c3 * 16 + q * 4];
        acc.x += (bf2f(za.x) + bf2f(zb.x)) + (bf2f(zc.x) + bf2f(zd.x));
        acc.y += (bf2f(za.y) + bf2f(zb.y)) + (bf2f(zc.y) + bf2f(zd.y));
        acc.z += (bf2f(za.z) + bf2f(zb.z)) + (bf2f(zc.z) + bf2f(zd.z));
        acc.w += (bf2f(za.w) + bf2f(zb.w)) + (bf2f(zc.w) + bf2f(zd.w));
    }
    for (; j < end; ++j) {
        int c0 = colb[j];
        ushort4 za = *(const ushort4*)&zin[(size_t)c0 * 16 + q * 4];
        acc.x += bf2f(za.x); acc.y += bf2f(za.y); acc.z += bf2f(za.z); acc.w += bf2f(za.w);
    }
    float dv = __int_as_float(m.z);
    float a = is_final ? dv : dv * dv;
    float b = is_final ? 1.0f : dv;
    float4 cv = *(const float4*)&cvec[q * 4];
    float4 val;
    val.x = a * acc.x + b * cv.x;
    val.y = a * acc.y + b * cv.y;
    val.z = a * acc.z + b * cv.z;
    val.w = a * acc.w + b * cv.w;
    int o = v * 16 + q * 4;
    if (is_final && !flags[0]) {
        *(float4*)&((float*)yout)[o] = val;
    } else {
        ushort4 ov;
        ov.x = f2bf(val.x); ov.y = f2bf(val.y); ov.z = f2bf(val.z); ov.w = f2bf(val.w);
        *(ushort4*)&((unsigned short*)yout)[o] = ov;
    }
}

// ---------------- launch ----------------
extern "C" void kernel_launch(void* const* d_in, const int* in_sizes, int n_in,
                              void* d_out, int out_size, void* d_ws, size_t ws_size,
                              hipStream_t stream) {
    const void* x  = d_in[0];
    const void* W1 = d_in[1];
    const void* b1 = d_in[2];
    const void* W2 = d_in[3];
    const void* b2 = d_in[4];
    const void* ei = d_in[5];

    const int n = in_sizes[0] / 64;       // 100000
    const int E = in_sizes[5] / 2;        // 1000000

    const int rsh = 7;
    const int B = (n + (1 << rsh) - 1) >> rsh;       // 782
    const int avg = E / B;
    int cap = avg + avg / 4 + 128;                    // mean + ~12 sigma slack
    cap = (cap + 31) & ~31;

    char* base = (char*)d_ws;
    size_t off = 0;
    auto carve = [&](size_t bytes) -> void* {
        void* r = base + off;
        off = (off + bytes + 255) & ~(size_t)255;
        return r;
    };
    int*            flags  = (int*)carve(8);
    int*            bcnt   = (int*)carve((size_t)B * 4);
    unsigned int*   bins   = (unsigned int*)carve((size_t)B * cap * 4);
    int*            colb   = (int*)carve((size_t)B * cap * 4);
    int4*           meta   = (int4*)carve((size_t)n * 16);
    float*          Mm     = (float*)carve(1024 * 4);
    float*          cvecs  = (float*)carve(64 * 4);
    unsigned short* z0     = (unsigned short*)carve((size_t)n * 16 * 2);
    unsigned short* z1     = (unsigned short*)carve((size_t)n * 16 * 2);
    (void)ws_size; (void)n_in; (void)out_size;

    const int nbin = 240;
    k_init<<<1, 1024, 0, stream>>>(x, ei, flags, bcnt, B);
    k_bin<<<nbin + 1, 512, (size_t)2 * B * 4, stream>>>(ei, E, rsh, B, cap, bins, bcnt,
                                                        flags, W1, b1, W2, b2, Mm, cvecs, nbin);
    k_csr<<<B, 256, 0, stream>>>(bins, bcnt, cap, rsh, n, colb, meta, x, Mm, z0, flags);

    const int pgrid = (n * 4 + 255) / 256;
    k_prop<<<pgrid, 256, 0, stream>>>(z0, z1, meta, colb, cvecs + 0,  n, 0, flags);
    k_prop<<<pgrid, 256, 0, stream>>>(z1, z0, meta, colb, cvecs + 16, n, 0, flags);
    k_prop<<<pgrid, 256, 0, stream>>>(z0, z1, meta, colb, cvecs + 32, n, 0, flags);
    k_prop<<<pgrid, 256, 0, stream>>>(z1, d_out, meta, colb, cvecs + 48, n, 1, flags);
}